// Round 1
// baseline (513.866 us; speedup 1.0000x reference)
//
#include <hip/hip_runtime.h>
#include <stdint.h>

#define N_    512
#define C_    128
#define NN_   (N_ * N_)           // 262144
#define ROWS_ (2 * NN_)           // 524288
#define GATE_ ((long)2 * 8 * NN_) // 4194304 elems per gate buffer (bf16)

typedef __attribute__((ext_vector_type(8))) short short8;
typedef __attribute__((ext_vector_type(4))) float f32x4;
typedef __attribute__((ext_vector_type(16))) float f32x16;
typedef __attribute__((ext_vector_type(4))) unsigned uint4_t;
typedef __attribute__((ext_vector_type(2))) unsigned uint2_t;
typedef unsigned short u16;

static __device__ __forceinline__ u16 f2bf(float f) {
    union { float f; unsigned u; } v; v.f = f;
    unsigned r = v.u + 0x7fffu + ((v.u >> 16) & 1u);
    return (u16)(r >> 16);
}
static __device__ __forceinline__ float bf2f(u16 h) {
    union { unsigned u; float f; } v; v.u = ((unsigned)h) << 16;
    return v.f;
}
static __device__ __forceinline__ float sigmoidf_(float x) {
    return __builtin_amdgcn_rcpf(1.0f + __expf(-x));
}
// global -> LDS direct DMA, 16B per lane. LDS dest = wave-uniform base + lane*16.
static __device__ __forceinline__ void gl_lds16(const u16* g, u16* l) {
    __builtin_amdgcn_global_load_lds(
        (const __attribute__((address_space(1))) unsigned int*)g,
        (__attribute__((address_space(3))) unsigned int*)l, 16, 0, 0);
}

// ---------------------------------------------------------------------------
// k_prep: build MFMA-fragment-ordered bf16 weight tables in global ws.
//  WB  [1024 groups x 8]: concat(Wv,We) B-frags for 16x16x32.
//      group = (kc*4+ct)*64 + lane; elem j: k = kc*32 + (lane>>4)*8 + j,
//      col c = ct*16 + (lane&15); c<32 -> Wv[k][c], else We[k][c-32].
//  WoB [1024 groups x 8]: Wo B-frags for 32x32x16 (hi part then lo part).
//      group = part*8 + ct (ct: 32-col tile 0..7), per group 64 lanes;
//      elem j: k = (lane>>5)*8 + j (K=16 exact, no padding),
//      col = ct*32 + (lane&31). part0 = bf16(hi), part1 = bf16(w - hi).
// ---------------------------------------------------------------------------
__global__ __launch_bounds__(256) void k_prep(
    const float* __restrict__ Wv, const float* __restrict__ We,
    const float* __restrict__ Wo, u16* __restrict__ WB, u16* __restrict__ WoB)
{
    int gid = blockIdx.x * 256 + threadIdx.x;
    if (gid < 1024) {
        int chunk = gid >> 6, li = gid & 63;
        int kc = chunk >> 2, ct = chunk & 3;
        int qq = li >> 4, nn = li & 15, c = ct * 16 + nn;
        short8 v;
#pragma unroll
        for (int j = 0; j < 8; ++j) {
            int k = kc * 32 + qq * 8 + j;
            float w = (c < 32) ? Wv[k * 32 + c] : We[k * 32 + (c - 32)];
            v[j] = (short)f2bf(w);
        }
        *(short8*)(&WB[gid * 8]) = v;
    } else if (gid < 2048) {
        int g = gid - 1024;
        int grp = g >> 6, li = g & 63;
        int ct = grp & 7, part = grp >> 3;
        int col = ct * 32 + (li & 31);
        int kh = (li >> 5) * 8;
        short8 v;
#pragma unroll
        for (int j = 0; j < 8; ++j) {
            float w = Wo[(kh + j) * 256 + col];
            u16 hi = f2bf(w);
            v[j] = part ? (short)f2bf(w - bf2f(hi)) : (short)hi;
        }
        *(short8*)(&WoB[g * 8]) = v;
    }
}

// ---------------------------------------------------------------------------
// k_lnproj: LN + dual projection + mask + siglin. No LDS, no barrier.
// Block = 256 (4 waves), 64 e-rows/block, wave w owns rows w*16..w*16+15.
// B-frags come straight from the hot 16KB WB table (L1/L2 resident).
// Gate outputs bf16 [B][H][N][N]; 4 packed 8B stores per thread.
// ---------------------------------------------------------------------------
__global__ __launch_bounds__(256) void k_lnproj(
    const float* __restrict__ e, const float* __restrict__ mask,
    const float* __restrict__ lnw, const float* __restrict__ lnb,
    const float* __restrict__ bv, const float* __restrict__ be,
    const u16* __restrict__ WB,
    u16* __restrict__ Vin, u16* __restrict__ Vout,
    u16* __restrict__ Ein, u16* __restrict__ Eout)
{
    const int t = threadIdx.x;
    const int w = t >> 6, l = t & 63;
    const int l15 = l & 15, q = l >> 4;
    const long R0 = (long)blockIdx.x * 64;

    // Load this lane's 32 e-values (cols kc*32 + q*8 + j).
    const long Rg = R0 + w * 16 + l15;
    const float* erow = e + Rg * C_ + q * 8;
    float x[32];
#pragma unroll
    for (int kc = 0; kc < 4; ++kc) {
        float4 a = *(const float4*)(erow + kc * 32);
        float4 b = *(const float4*)(erow + kc * 32 + 4);
        x[kc*8+0] = a.x; x[kc*8+1] = a.y; x[kc*8+2] = a.z; x[kc*8+3] = a.w;
        x[kc*8+4] = b.x; x[kc*8+5] = b.y; x[kc*8+6] = b.z; x[kc*8+7] = b.w;
    }
    float s = 0.f, s2 = 0.f;
#pragma unroll
    for (int i = 0; i < 32; ++i) { s += x[i]; s2 += x[i] * x[i]; }
    s  += __shfl_xor(s, 16);  s2 += __shfl_xor(s2, 16);
    s  += __shfl_xor(s, 32);  s2 += __shfl_xor(s2, 32);
    float mu   = s * (1.f / 128.f);
    float var  = s2 * (1.f / 128.f) - mu * mu;
    float rstd = rsqrtf(var + 1e-5f);

    short8 af[4];
#pragma unroll
    for (int kc = 0; kc < 4; ++kc) {
        const float* lwp = lnw + kc * 32 + q * 8;
        const float* lbp = lnb + kc * 32 + q * 8;
        float4 w0 = *(const float4*)lwp, w1 = *(const float4*)(lwp + 4);
        float4 b0 = *(const float4*)lbp, b1 = *(const float4*)(lbp + 4);
        float ww[8] = {w0.x,w0.y,w0.z,w0.w,w1.x,w1.y,w1.z,w1.w};
        float bb[8] = {b0.x,b0.y,b0.z,b0.w,b1.x,b1.y,b1.z,b1.w};
#pragma unroll
        for (int j = 0; j < 8; ++j)
            af[kc][j] = (short)f2bf((x[kc*8+j] - mu) * rstd * ww[j] + bb[j]);
    }

    f32x4 acc[4];
#pragma unroll
    for (int ct = 0; ct < 4; ++ct) acc[ct] = (f32x4){0.f, 0.f, 0.f, 0.f};
#pragma unroll
    for (int kc = 0; kc < 4; ++kc) {
#pragma unroll
        for (int ct = 0; ct < 4; ++ct) {
            short8 bf = *(const short8*)(WB + ((kc * 4 + ct) * 64 + l) * 8);
            acc[ct] = __builtin_amdgcn_mfma_f32_16x16x32_bf16(af[kc], bf, acc[ct], 0, 0, 0);
        }
    }

    // Epilogue. C[row=q*4+r][col=ct*16+l15]; (c, c+8) = (gate, linear).
    float mrow[4];
#pragma unroll
    for (int r = 0; r < 4; ++r) mrow[r] = mask[R0 + w * 16 + q * 4 + r];
    const bool is_gate = (l15 & 8) == 0;
    const int h = l15 & 7;
    const long bb_ = R0 >> 18;
    const long rem0 = (R0 & (NN_ - 1)) + w * 16 + q * 4;
    u16* bufs[4] = { Vin, Vout, Ein, Eout };
#pragma unroll
    for (int ct = 0; ct < 4; ++ct) {
        int cc = (ct * 16 + l15) & 31;
        float bias = (ct < 2) ? bv[cc] : be[cc];
        float vals[4];
#pragma unroll
        for (int r = 0; r < 4; ++r) {
            float val = acc[ct][r] + bias;
            float partner = __shfl_xor(val, 8);   // all lanes execute
            vals[r] = partner * sigmoidf_(val + mrow[r]);
        }
        if (is_gate) {
            uint2_t p;
            p[0] = (unsigned)f2bf(vals[0]) | ((unsigned)f2bf(vals[1]) << 16);
            p[1] = (unsigned)f2bf(vals[2]) | ((unsigned)f2bf(vals[3]) << 16);
            *(uint2_t*)(bufs[ct] + (bb_ * 8 + h) * (long)NN_ + rem0) = p;
        }
    }
}

// ---------------------------------------------------------------------------
// k_tri: 32 batched 512^3 GEMMs. 128x128 C-tile/block, 4 waves of 64x64
// (4x4 16x16 accs), BK=64. LDS tiles [128 rows][8 slots of 16B], XOR-swizzled:
// LDS[r][s] holds data slot (s ^ f(r)), f(r) = (r ^ (r>>3)) & 7. Reads at
// slot (S ^ f(R)) are bank-uniform; so are the fl=1 ds_write_b128s.
// fl=0 (NT): global_load_lds width-16 with inverse-swizzled SOURCE address
// (linear LDS dest, rule: swizzle both sides or neither).
// fl=1 (TN): in-register 8x8 bf16 transpose (v_perm), swizzled b128 writes.
// Output Va bf16 [B][16][N][N], ch = fl*8 + h.
// ---------------------------------------------------------------------------
__global__ __launch_bounds__(256) void k_tri(
    const u16* __restrict__ Vin, const u16* __restrict__ Vout,
    const u16* __restrict__ Ein, const u16* __restrict__ Eout,
    u16* __restrict__ Va)
{
    __shared__ __align__(16) u16 lA[128 * 64];
    __shared__ __align__(16) u16 lB[128 * 64];
    const int bid = blockIdx.x;
    const int tj = bid & 3, ti = (bid >> 2) & 3, fl = (bid >> 4) & 1;
    const int h = (bid >> 5) & 7, b = (bid >> 8) & 1;
    const u16* Ap = (fl ? Eout : Ein) + (long)(b * 8 + h) * NN_;
    const u16* Bp = (fl ? Vout : Vin) + (long)(b * 8 + h) * NN_;
    u16* Cp = Va + (long)(b * 16 + fl * 8 + h) * NN_;

    const int t = threadIdx.x;
    const int w = t >> 6, l = t & 63, l15 = l & 15, q = l >> 4;
    const int rt = (w >> 1) * 64, ctl = (w & 1) * 64;

    f32x4 acc[4][4];
#pragma unroll
    for (int rr = 0; rr < 4; ++rr)
#pragma unroll
        for (int cc = 0; cc < 4; ++cc) acc[rr][cc] = (f32x4){0.f, 0.f, 0.f, 0.f};

    for (int ks = 0; ks < 512; ks += 64) {
        if (fl == 0) {
            // chunk cid = p*256 + t; r = cid>>3, s = cid&7; lane l of wave w
            // lands at LDS chunk (p*256 + w*64 + l) automatically (DMA).
#pragma unroll
            for (int p = 0; p < 4; ++p) {
                const int cid = p * 256 + t;
                const int r = cid >> 3, sct = cid & 7;
                const int sk = ((sct ^ ((r ^ (r >> 3)) & 7)) << 3);
                const int lbase = (p * 256 + (t & 192)) << 3;
                gl_lds16(Ap + (long)(ti * 128 + r) * 512 + ks + sk, &lA[lbase]);
                gl_lds16(Bp + (long)(tj * 128 + r) * 512 + ks + sk, &lB[lbase]);
            }
        } else {
            // Transpose staging: thread owns one 8x8 block (i x k).
            const u16* P = (t < 128) ? Ap : Bp;
            u16* L = (t < 128) ? lA : lB;
            const int tt = t & 127, ib = tt & 15, kb = tt >> 4;  // ib:0..15, kb:0..7
            const int io = ((t < 128) ? ti : tj) * 128 + ib * 8;
            uint4_t o[8];
#pragma unroll
            for (int p2 = 0; p2 < 4; ++p2) {
                uint4_t ra = *(const uint4_t*)(P + (long)(ks + kb * 8 + 2 * p2    ) * 512 + io);
                uint4_t rb = *(const uint4_t*)(P + (long)(ks + kb * 8 + 2 * p2 + 1) * 512 + io);
#pragma unroll
                for (int d = 0; d < 4; ++d) {
                    o[2*d  ][p2] = __builtin_amdgcn_perm(rb[d], ra[d], 0x05040100u);
                    o[2*d+1][p2] = __builtin_amdgcn_perm(rb[d], ra[d], 0x07060302u);
                }
            }
#pragma unroll
            for (int j = 0; j < 8; ++j) {
                const int R = ib * 8 + j;
                const int sl = kb ^ ((R ^ (R >> 3)) & 7);
                *(uint4_t*)(&L[(R << 6) + (sl << 3)]) = o[j];
            }
        }
        __syncthreads();
#pragma unroll
        for (int kf = 0; kf < 2; ++kf) {
            const int S = kf * 4 + q;
            short8 a[4], bf[4];
#pragma unroll
            for (int rr = 0; rr < 4; ++rr) {
                const int R = rt + rr * 16 + l15;
                a[rr] = *(const short8*)(&lA[(R << 6) + ((S ^ ((R ^ (R >> 3)) & 7)) << 3)]);
            }
#pragma unroll
            for (int cc = 0; cc < 4; ++cc) {
                const int R = ctl + cc * 16 + l15;
                bf[cc] = *(const short8*)(&lB[(R << 6) + ((S ^ ((R ^ (R >> 3)) & 7)) << 3)]);
            }
#pragma unroll
            for (int rr = 0; rr < 4; ++rr)
#pragma unroll
                for (int cc = 0; cc < 4; ++cc)
                    acc[rr][cc] = __builtin_amdgcn_mfma_f32_16x16x32_bf16(a[rr], bf[cc], acc[rr][cc], 0, 0, 0);
        }
        __syncthreads();
    }
#pragma unroll
    for (int rr = 0; rr < 4; ++rr)
#pragma unroll
        for (int cc = 0; cc < 4; ++cc)
#pragma unroll
            for (int r = 0; r < 4; ++r) {
                int row = ti * 128 + rt + rr * 16 + q * 4 + r;
                int col = tj * 128 + ctl + cc * 16 + l15;
                Cp[(long)row * 512 + col] = f2bf(acc[rr][cc][r]);
            }
}

// ---------------------------------------------------------------------------
// k_out: O = Va @ Wo + bo via mfma_f32_32x32x16_bf16 (K=16 exact, Wo split
// hi+lo bf16); out = sigmoid(O[:, :128]) * O[:, 128:].
// NO LDS, NO barriers: per-lane A-frag (row = l&31, k = (l>>5)*8+j) is an
// 8-plane strided gather from Va (coalesced 64B/segment per plane), B-frags
// read straight from the hot 16KB WoB table. Block = 128 rows (4 waves x 32).
// C/D 32x32 layout: col = l&31, row = (reg&3) + 8*(reg>>2) + 4*(l>>5).
// ---------------------------------------------------------------------------
__global__ __launch_bounds__(256) void k_out(
    const u16* __restrict__ Va, const u16* __restrict__ WoB,
    const float* __restrict__ bo, float* __restrict__ out)
{
    const int t = threadIdx.x;
    const int w = t >> 6, l = t & 63;
    const int l31 = l & 31, hl = l >> 5;
    const long R0 = (long)blockIdx.x * 128;
    const long bb = R0 >> 18;
    const long rem = (R0 & (NN_ - 1)) + w * 32 + l31;

    const u16* vp = Va + (bb * 16 + hl * 8) * (long)NN_ + rem;
    short8 af;
#pragma unroll
    for (int j = 0; j < 8; ++j) af[j] = (short)vp[(long)j * NN_];

    f32x16 acc[8];
#pragma unroll
    for (int ct = 0; ct < 8; ++ct)
#pragma unroll
        for (int i = 0; i < 16; ++i) acc[ct][i] = 0.f;

#pragma unroll
    for (int ct = 0; ct < 8; ++ct) {
        short8 bh = *(const short8*)(WoB + ((ct    ) * 64 + l) * 8);
        short8 bl = *(const short8*)(WoB + ((8 + ct) * 64 + l) * 8);
        acc[ct] = __builtin_amdgcn_mfma_f32_32x32x16_bf16(af, bh, acc[ct], 0, 0, 0);
        acc[ct] = __builtin_amdgcn_mfma_f32_32x32x16_bf16(af, bl, acc[ct], 0, 0, 0);
    }

#pragma unroll
    for (int ct = 0; ct < 4; ++ct) {
        const int cg = ct * 32 + l31;
        const float bg = bo[cg], bln = bo[128 + cg];
#pragma unroll
        for (int r = 0; r < 16; ++r) {
            const int rowc = (r & 3) + 8 * (r >> 2) + 4 * hl;
            const float g  = acc[ct][r] + bg;
            const float lv = acc[ct + 4][r] + bln;
            out[(R0 + w * 32 + rowc) * 128 + cg] = lv * sigmoidf_(g);
        }
    }
}

// ---------------------------------------------------------------------------
extern "C" void kernel_launch(void* const* d_in, const int* in_sizes, int n_in,
                              void* d_out, int out_size, void* d_ws, size_t ws_size,
                              hipStream_t stream)
{
    const float* e    = (const float*)d_in[0];
    const float* mask = (const float*)d_in[1];
    const float* lnw  = (const float*)d_in[2];
    const float* lnb  = (const float*)d_in[3];
    const float* Wv   = (const float*)d_in[4];
    const float* bv   = (const float*)d_in[5];
    const float* We   = (const float*)d_in[6];
    const float* be   = (const float*)d_in[7];
    const float* Wo   = (const float*)d_in[8];
    const float* bo   = (const float*)d_in[9];
    float* out = (float*)d_out;

    // ws (bf16 elems): 4 gate buffers + Va (2*GATE_) + WB(8K) + WoB(8K)
    u16* ws   = (u16*)d_ws;
    u16* Ein  = ws;
    u16* Vin  = ws + 1L * GATE_;
    u16* Eout = ws + 2L * GATE_;
    u16* Vout = ws + 3L * GATE_;
    u16* Va   = ws + 4L * GATE_;
    u16* WB   = ws + 6L * GATE_;
    u16* WoB  = WB + 8192;

    hipLaunchKernelGGL(k_prep, dim3(8), dim3(256), 0, stream, Wv, We, Wo, WB, WoB);
    hipLaunchKernelGGL(k_lnproj, dim3(ROWS_ / 64), dim3(256), 0, stream,
                       e, mask, lnw, lnb, bv, be, WB, Vin, Vout, Ein, Eout);
    hipLaunchKernelGGL(k_tri, dim3(512), dim3(256), 0, stream,
                       Vin, Vout, Ein, Eout, Va);
    hipLaunchKernelGGL(k_out, dim3(ROWS_ / 128), dim3(256), 0, stream,
                       Va, WoB, bo, out);
}